// Round 1
// baseline (247.678 us; speedup 1.0000x reference)
//
#include <hip/hip_runtime.h>

// RBF network: out[n] = (sum_c exp(-beta_c * |x_n - c_c|^2) * w_c)
//                     / (sum_c exp(-beta_c * |x_n - c_c|^2))
//
// Strength reduction: -beta*(|x|^2 + |c|^2 - 2 x.c) * log2(e)
//   = p3 + p0*x0 + p1*x1 + p2*x2 - q*|x|^2
// with per-center constants (precomputed once per call into d_ws):
//   p0 = 2*beta*log2e*cx, p1 = ..cy, p2 = ..cz, p3 = -beta*log2e*|c|^2,
//   q  = beta*log2e, w = lin_w[c]
// Then rbf = exp2(t) via v_exp_f32.
// Table stride = 8 floats (32 B) so the wave-uniform fetch is one s_load_dwordx8.

__global__ __launch_bounds__(256) void rbf_precompute(
        const float* __restrict__ centers,
        const float* __restrict__ beta,
        const float* __restrict__ lin_w,
        float* __restrict__ params, int C) {
    int c = blockIdx.x * blockDim.x + threadIdx.x;
    if (c >= C) return;
    const float LOG2E = 1.4426950408889634f;
    float cx = centers[3*c+0], cy = centers[3*c+1], cz = centers[3*c+2];
    float b  = beta[c] * LOG2E;
    float c2 = cx*cx + cy*cy + cz*cz;
    float* p = params + 8*c;
    p[0] = 2.0f*b*cx;
    p[1] = 2.0f*b*cy;
    p[2] = 2.0f*b*cz;
    p[3] = -b*c2;
    p[4] = b;
    p[5] = lin_w[c];
    p[6] = 0.0f;
    p[7] = 0.0f;
}

// 2 points per thread: two independent dep-chains (ILP), halves the
// per-point share of the uniform param fetch.
__global__ __launch_bounds__(256) void rbf_main(
        const float* __restrict__ x,
        const float* __restrict__ params,
        float* __restrict__ out,
        int n, int C) {
    int t = blockIdx.x * blockDim.x + threadIdx.x;
    int i0 = 2*t, i1 = 2*t + 1;
    if (i0 >= n) return;

    // x is (n,3) fp32; thread t reads 6 consecutive floats = 3 float2 loads
    const float2* xv = (const float2*)x;
    float2 v0 = xv[3*t + 0];
    float2 v1 = xv[3*t + 1];
    float2 v2 = xv[3*t + 2];
    float ax = v0.x, ay = v0.y, az = v1.x;
    float bx = v1.y, by = v2.x, bz = v2.y;

    float a2 = ax*ax + ay*ay + az*az;
    float b2 = bx*bx + by*by + bz*bz;

    float sumA = 0.f, accA = 0.f;
    float sumB = 0.f, accB = 0.f;

    #pragma unroll 4
    for (int c = 0; c < C; ++c) {
        const float* p = params + 8*c;   // wave-uniform -> scalar load path
        float p0 = p[0], p1 = p[1], p2 = p[2], p3 = p[3];
        float q  = p[4], w  = p[5];

        float ta = fmaf(p0, ax, fmaf(p1, ay, fmaf(p2, az, fmaf(-q, a2, p3))));
        float tb = fmaf(p0, bx, fmaf(p1, by, fmaf(p2, bz, fmaf(-q, b2, p3))));

        float ea = __builtin_amdgcn_exp2f(ta);   // v_exp_f32
        float eb = __builtin_amdgcn_exp2f(tb);

        sumA += ea;  accA = fmaf(ea, w, accA);
        sumB += eb;  accB = fmaf(eb, w, accB);
    }

    out[i0] = accA / sumA;
    if (i1 < n) out[i1] = accB / sumB;
}

extern "C" void kernel_launch(void* const* d_in, const int* in_sizes, int n_in,
                              void* d_out, int out_size, void* d_ws, size_t ws_size,
                              hipStream_t stream) {
    const float* x       = (const float*)d_in[0];   // (N,3)
    const float* centers = (const float*)d_in[1];   // (C,3)
    const float* beta    = (const float*)d_in[2];   // (C,)
    const float* lin_w   = (const float*)d_in[3];   // (1,C)
    float* out    = (float*)d_out;                  // (N,1) fp32
    float* params = (float*)d_ws;                   // 8*C floats = 64 KB

    int C = in_sizes[2];
    int n = in_sizes[0] / 3;

    int pre_blocks = (C + 255) / 256;
    rbf_precompute<<<pre_blocks, 256, 0, stream>>>(centers, beta, lin_w, params, C);

    int threads = (n + 1) / 2;                      // 2 points per thread
    int main_blocks = (threads + 255) / 256;
    rbf_main<<<main_blocks, 256, 0, stream>>>(x, params, out, n, C);
}

// Round 2
// 124.981 us; speedup vs baseline: 1.9817x; 1.9817x over previous
//
#include <hip/hip_runtime.h>

// RBF network: out[n] = (sum_c exp(-beta_c*|x_n-c_c|^2)*w_c) / (sum_c exp(-beta_c*|x_n-c_c|^2))
//
// Strength reduction (precomputed per center into d_ws, stride 8 floats = one s_load_dwordx8):
//   exp(-beta*(|x|^2+|c|^2-2x.c)) = exp2(p3 + p0*x0 + p1*x1 + p2*x2 - q*|x|^2)
//
// Round-2 restructure: center-split for occupancy.
//   block = 256 threads = 4 waves; wave w takes centers [w*C/4, (w+1)*C/4)
//   lane l takes points block*128 + l and +64  (2 points/lane for ILP + shared s_loads)
//   -> 1024 blocks = 16 waves/CU (vs 4 before), LDS reduction across the 4 waves.
// readfirstlane(wv) keeps the chunk base wave-uniform so param reads stay on the
// scalar pipe (s_load_dwordx8), leaving VALU for the 12 FMA + 2 exp per iteration.

__global__ __launch_bounds__(256) void rbf_precompute(
        const float* __restrict__ centers,
        const float* __restrict__ beta,
        const float* __restrict__ lin_w,
        float* __restrict__ params, int C) {
    int c = blockIdx.x * blockDim.x + threadIdx.x;
    if (c >= C) return;
    const float LOG2E = 1.4426950408889634f;
    float cx = centers[3*c+0], cy = centers[3*c+1], cz = centers[3*c+2];
    float b  = beta[c] * LOG2E;
    float c2 = cx*cx + cy*cy + cz*cz;
    float* p = params + 8*c;
    p[0] = 2.0f*b*cx;
    p[1] = 2.0f*b*cy;
    p[2] = 2.0f*b*cz;
    p[3] = -b*c2;
    p[4] = b;
    p[5] = lin_w[c];
    p[6] = 0.0f;
    p[7] = 0.0f;
}

__global__ __launch_bounds__(256) void rbf_main(
        const float* __restrict__ x,
        const float* __restrict__ params,
        float* __restrict__ out,
        int n, int C) {
    const int lane = threadIdx.x & 63;
    // wave id: genuinely wave-uniform; readfirstlane makes the compiler see it,
    // so the param loop stays on the scalar-load path.
    const int wv = __builtin_amdgcn_readfirstlane(threadIdx.x >> 6);

    const int p0i = blockIdx.x * 128 + lane;   // point A
    const int p1i = p0i + 64;                  // point B

    const int chunk = (C + 3) >> 2;
    const int cbeg = wv * chunk;
    const int cend = min(cbeg + chunk, C);

    float ax = 0.f, ay = 0.f, az = 0.f, bx = 0.f, by = 0.f, bz = 0.f;
    const bool vA = (p0i < n), vB = (p1i < n);
    if (vA) { ax = x[3*p0i]; ay = x[3*p0i+1]; az = x[3*p0i+2]; }
    if (vB) { bx = x[3*p1i]; by = x[3*p1i+1]; bz = x[3*p1i+2]; }
    const float na2 = -(ax*ax + ay*ay + az*az);
    const float nb2 = -(bx*bx + by*by + bz*bz);

    float sumA = 0.f, accA = 0.f, sumB = 0.f, accB = 0.f;

    #pragma unroll 4
    for (int c = cbeg; c < cend; ++c) {
        const float* p = params + 8*c;         // wave-uniform -> s_load_dwordx8
        float q0 = p[0], q1 = p[1], q2 = p[2], q3 = p[3];
        float qq = p[4], w  = p[5];

        float ta = fmaf(q0, ax, fmaf(q1, ay, fmaf(q2, az, fmaf(qq, na2, q3))));
        float tb = fmaf(q0, bx, fmaf(q1, by, fmaf(q2, bz, fmaf(qq, nb2, q3))));

        float ea = __builtin_amdgcn_exp2f(ta);
        float eb = __builtin_amdgcn_exp2f(tb);

        sumA += ea;  accA = fmaf(ea, w, accA);
        sumB += eb;  accB = fmaf(eb, w, accB);
    }

    // cross-wave reduction: [wave][value][lane] -> lane-stride-1, conflict-free
    __shared__ float red[4][4][64];
    if (wv > 0) {
        red[wv][0][lane] = sumA;  red[wv][1][lane] = accA;
        red[wv][2][lane] = sumB;  red[wv][3][lane] = accB;
    }
    __syncthreads();
    if (wv == 0) {
        #pragma unroll
        for (int w2 = 1; w2 < 4; ++w2) {
            sumA += red[w2][0][lane];  accA += red[w2][1][lane];
            sumB += red[w2][2][lane];  accB += red[w2][3][lane];
        }
        if (vA) out[p0i] = accA / sumA;
        if (vB) out[p1i] = accB / sumB;
    }
}

extern "C" void kernel_launch(void* const* d_in, const int* in_sizes, int n_in,
                              void* d_out, int out_size, void* d_ws, size_t ws_size,
                              hipStream_t stream) {
    const float* x       = (const float*)d_in[0];   // (N,3)
    const float* centers = (const float*)d_in[1];   // (C,3)
    const float* beta    = (const float*)d_in[2];   // (C,)
    const float* lin_w   = (const float*)d_in[3];   // (1,C)
    float* out    = (float*)d_out;                  // (N,1) fp32
    float* params = (float*)d_ws;                   // 8*C floats = 64 KB

    int C = in_sizes[2];
    int n = in_sizes[0] / 3;

    int pre_blocks = (C + 255) / 256;
    rbf_precompute<<<pre_blocks, 256, 0, stream>>>(centers, beta, lin_w, params, C);

    int main_blocks = (n + 127) / 128;              // 128 points per block
    rbf_main<<<main_blocks, 256, 0, stream>>>(x, params, out, n, C);
}

// Round 3
// 105.363 us; speedup vs baseline: 2.3507x; 1.1862x over previous
//
#include <hip/hip_runtime.h>

// RBF network: out[n] = (sum_c exp(-beta_c*|x_n-c_c|^2)*w_c) / (sum_c exp(-beta_c*|x_n-c_c|^2))
//
// Strength reduction (precomputed per center, stride 8 floats = one s_load_dwordx8):
//   exp(-beta*(|x|^2+|c|^2-2x.c)) = exp2(p3 + p0*x0 + p1*x1 + p2*x2 - q*|x|^2)
//
// Round-3: 8 waves/block (512 thr), wave w takes C/8=250 centers; lane holds
// 2 points packed in float2 so the FMA chain emits v_pk_fma_f32 (VOP3P):
// per center-iter: 4 pk_fma + 2 v_exp + pk_add + pk_fma = 6 VALU + 2 trans
// (was 12 VALU + 2 trans). 1024 blocks x 8 waves = 32 waves/CU = 100% nominal.

typedef float v2f __attribute__((ext_vector_type(2)));

__global__ __launch_bounds__(256) void rbf_precompute(
        const float* __restrict__ centers,
        const float* __restrict__ beta,
        const float* __restrict__ lin_w,
        float* __restrict__ params, int C) {
    int c = blockIdx.x * blockDim.x + threadIdx.x;
    if (c >= C) return;
    const float LOG2E = 1.4426950408889634f;
    float cx = centers[3*c+0], cy = centers[3*c+1], cz = centers[3*c+2];
    float b  = beta[c] * LOG2E;
    float c2 = cx*cx + cy*cy + cz*cz;
    float* p = params + 8*c;
    p[0] = 2.0f*b*cx;
    p[1] = 2.0f*b*cy;
    p[2] = 2.0f*b*cz;
    p[3] = -b*c2;
    p[4] = b;
    p[5] = lin_w[c];
    p[6] = 0.0f;
    p[7] = 0.0f;
}

__global__ __launch_bounds__(512) void rbf_main(
        const float* __restrict__ x,
        const float* __restrict__ params,
        float* __restrict__ out,
        int n, int C) {
    const int lane = threadIdx.x & 63;
    // wave id is wave-uniform; readfirstlane lets the compiler prove it so the
    // param loop stays on the scalar-load (s_load_dwordx8) path.
    const int wv = __builtin_amdgcn_readfirstlane(threadIdx.x >> 6);   // 0..7

    const int p0i = blockIdx.x * 128 + lane;   // point A
    const int p1i = p0i + 64;                  // point B

    const int chunk = (C + 7) >> 3;
    const int cbeg = wv * chunk;
    const int cend = min(cbeg + chunk, C);

    float ax = 0.f, ay = 0.f, az = 0.f, bx = 0.f, by = 0.f, bz = 0.f;
    const bool vA = (p0i < n), vB = (p1i < n);
    if (vA) { ax = x[3*p0i]; ay = x[3*p0i+1]; az = x[3*p0i+2]; }
    if (vB) { bx = x[3*p1i]; by = x[3*p1i+1]; bz = x[3*p1i+2]; }

    // pack the two points into vector lanes -> v_pk_* (VOP3P) ops
    v2f X = {ax, bx}, Y = {ay, by}, Z = {az, bz};
    v2f N2 = { -(ax*ax + ay*ay + az*az), -(bx*bx + by*by + bz*bz) };

    v2f sum = {0.f, 0.f}, acc = {0.f, 0.f};

    #pragma unroll 4
    for (int c = cbeg; c < cend; ++c) {
        const float* p = params + 8*c;         // wave-uniform -> s_load_dwordx8
        v2f q0 = {p[0], p[0]};
        v2f q1 = {p[1], p[1]};
        v2f q2 = {p[2], p[2]};
        v2f q3 = {p[3], p[3]};
        v2f qq = {p[4], p[4]};
        v2f w  = {p[5], p[5]};

        v2f t = __builtin_elementwise_fma(q0, X,
                __builtin_elementwise_fma(q1, Y,
                __builtin_elementwise_fma(q2, Z,
                __builtin_elementwise_fma(qq, N2, q3))));

        v2f e = { __builtin_amdgcn_exp2f(t.x), __builtin_amdgcn_exp2f(t.y) };

        sum += e;                                   // v_pk_add_f32
        acc = __builtin_elementwise_fma(e, w, acc); // v_pk_fma_f32
    }

    // cross-wave reduction: [wave][value][lane] -> lane-stride-1, conflict-free
    __shared__ float red[8][4][64];
    if (wv > 0) {
        red[wv][0][lane] = sum.x;  red[wv][1][lane] = acc.x;
        red[wv][2][lane] = sum.y;  red[wv][3][lane] = acc.y;
    }
    __syncthreads();
    if (wv == 0) {
        float sA = sum.x, aA = acc.x, sB = sum.y, aB = acc.y;
        #pragma unroll
        for (int w2 = 1; w2 < 8; ++w2) {
            sA += red[w2][0][lane];  aA += red[w2][1][lane];
            sB += red[w2][2][lane];  aB += red[w2][3][lane];
        }
        if (vA) out[p0i] = aA / sA;
        if (vB) out[p1i] = aB / sB;
    }
}

extern "C" void kernel_launch(void* const* d_in, const int* in_sizes, int n_in,
                              void* d_out, int out_size, void* d_ws, size_t ws_size,
                              hipStream_t stream) {
    const float* x       = (const float*)d_in[0];   // (N,3)
    const float* centers = (const float*)d_in[1];   // (C,3)
    const float* beta    = (const float*)d_in[2];   // (C,)
    const float* lin_w   = (const float*)d_in[3];   // (1,C)
    float* out    = (float*)d_out;                  // (N,1) fp32
    float* params = (float*)d_ws;                   // 8*C floats = 64 KB

    int C = in_sizes[2];
    int n = in_sizes[0] / 3;

    int pre_blocks = (C + 255) / 256;
    rbf_precompute<<<pre_blocks, 256, 0, stream>>>(centers, beta, lin_w, params, C);

    int main_blocks = (n + 127) / 128;              // 128 points per block
    rbf_main<<<main_blocks, 512, 0, stream>>>(x, params, out, n, C);
}